// Round 1
// baseline (178.536 us; speedup 1.0000x reference)
//
#include <hip/hip_runtime.h>
#include <math.h>

#define B_    2
#define N_    512
#define DIM_  64
#define MD    16
#define EIN   137
#define EH    274    // EIN*2
#define OUT_H (B_*N_*DIM_)   // 65536

// ---------------------------------------------------------------------------
// Kernel A: precompute
//   Q1 [b*n][274]  = feats @ w1e[0:64,:]  + b1e      (i-side projection)
//   P2T[b][274][n] = feats @ w1e[64:128,:]           (j-side, TRANSPOSED)
//   w1cT[64][16]   = w1c^T                           (for coalesced s_loads)
// ---------------------------------------------------------------------------
__global__ __launch_bounds__(256) void egnn_pre(
    const float* __restrict__ feats, const float* __restrict__ w1e,
    const float* __restrict__ b1e,   const float* __restrict__ w1c,
    float* __restrict__ Q1, float* __restrict__ P2T, float* __restrict__ w1cT)
{
    int g = blockIdx.x * 256 + threadIdx.x;
    const int MAIN = (B_ * N_) * EH;  // 280576
    if (g < MAIN) {
        int ng = g / EH;
        int e  = g - ng * EH;
        int b  = ng >> 9, n = ng & (N_ - 1);
        float a1 = b1e[e], a2 = 0.f;
        const float* fp = feats + ng * DIM_;
        #pragma unroll 8
        for (int d = 0; d < DIM_; ++d) {
            float f = fp[d];
            a1 += f * w1e[d * EH + e];
            a2 += f * w1e[(DIM_ + d) * EH + e];
        }
        Q1[ng * EH + e]            = a1;
        P2T[(b * EH + e) * N_ + n] = a2;
    } else {
        int x = g - MAIN;
        if (x < 1024) {
            int o2 = x >> 4, o = x & 15;
            w1cT[x] = w1c[o * 64 + o2];
        }
    }
}

// ---------------------------------------------------------------------------
// Kernel B: one block per (b,i); each thread owns j = t and j = t+256.
// Fused: edge MLP -> m_ij -> coor MLP -> per-i reductions -> node MLP.
// ---------------------------------------------------------------------------
__global__ __launch_bounds__(256) void egnn_edge(
    const float* __restrict__ feats, const float* __restrict__ coors,
    const float* __restrict__ w1e,   const float* __restrict__ w2e,
    const float* __restrict__ b2e,   const float* __restrict__ b1c,
    const float* __restrict__ w2c,   const float* __restrict__ b2c,
    const float* __restrict__ w1h,   const float* __restrict__ b1h,
    const float* __restrict__ w2h,   const float* __restrict__ b2h,
    const float* __restrict__ Q1,    const float* __restrict__ P2T,
    const float* __restrict__ w1cT,  float* __restrict__ out)
{
    const int bi = blockIdx.x;        // 0..1023  == b*512 + i
    const int b  = bi >> 9;
    const int t  = threadIdx.x;

    __shared__ float sRed[256 * 20];
    __shared__ float sHid[128];

    const float cix = coors[bi * 3 + 0];
    const float ciy = coors[bi * 3 + 1];
    const float ciz = coors[bi * 3 + 2];

    float macc[MD];
    #pragma unroll
    for (int o = 0; o < MD; ++o) macc[o] = 0.f;
    float cax = 0.f, cay = 0.f, caz = 0.f;

    const float* Q1p = Q1 + bi * EH;          // uniform per block
    const float* Wd  = w1e + 128 * EH;        // dist-encoding rows [9][274]
    const float* P2b = P2T + b * EH * N_;

    for (int jj = 0; jj < 2; ++jj) {
        const int j  = t + jj * 256;
        const int jg = (b << 9) + j;
        float rx = cix - coors[jg * 3 + 0];
        float ry = ciy - coors[jg * 3 + 1];
        float rz = ciz - coors[jg * 3 + 2];
        float sq = rx * rx + ry * ry + rz * rz;
        float d  = (sq > 0.f) ? sqrtf(sq) : 0.f;

        float enc[9];
        enc[8] = d;
        #pragma unroll
        for (int k = 0; k < 4; ++k) {
            float x = d * (1.0f / (float)(1 << k));
            __sincosf(x, &enc[k], &enc[4 + k]);
        }

        float m[MD];
        #pragma unroll
        for (int o = 0; o < MD; ++o) m[o] = 0.f;

        #pragma unroll 2
        for (int e = 0; e < EH; ++e) {
            float pre = Q1p[e] + P2b[e * N_ + j];   // uniform + coalesced
            #pragma unroll
            for (int k = 0; k < 9; ++k) pre += enc[k] * Wd[k * EH + e];
            float h = fmaxf(pre, 0.f);
            const float* w2 = w2e + e * MD;         // uniform row
            #pragma unroll
            for (int o = 0; o < MD; ++o) m[o] += h * w2[o];
        }
        #pragma unroll
        for (int o = 0; o < MD; ++o) m[o] += b2e[o];

        // coor MLP: cw = relu(m @ w1c + b1c) @ w2c + b2c
        float cw = b2c[0];
        for (int o2 = 0; o2 < 64; ++o2) {
            float q = b1c[o2];
            const float* wc = w1cT + o2 * MD;       // uniform row (transposed)
            #pragma unroll
            for (int o = 0; o < MD; ++o) q += m[o] * wc[o];
            cw += fmaxf(q, 0.f) * w2c[o2];
        }

        cax += cw * rx; cay += cw * ry; caz += cw * rz;
        #pragma unroll
        for (int o = 0; o < MD; ++o) macc[o] += m[o];
    }

    // ---- block-reduce 19 values (m_i[16], coors_out[3]) ----
    float* row = sRed + t * 20;
    #pragma unroll
    for (int o = 0; o < MD; ++o) row[o] = macc[o];
    row[16] = cax; row[17] = cay; row[18] = caz;
    __syncthreads();
    for (int s = 128; s >= 1; s >>= 1) {
        if (t < s) {
            #pragma unroll
            for (int k = 0; k < 19; ++k) sRed[t * 20 + k] += sRed[(t + s) * 20 + k];
        }
        __syncthreads();
    }

    // ---- node MLP: hid_in = [feats_i(64), m_i(16)] -> 128 -> 64 ----
    if (t < 128) {
        float a = b1h[t];
        const float* fp = feats + bi * DIM_;
        #pragma unroll 8
        for (int k = 0; k < DIM_; ++k) a += fp[k] * w1h[k * 128 + t];
        #pragma unroll
        for (int k = 0; k < MD; ++k)  a += sRed[k] * w1h[(DIM_ + k) * 128 + t];
        sHid[t] = fmaxf(a, 0.f);
    }
    __syncthreads();
    if (t < 64) {
        float a = b2h[t];
        #pragma unroll 8
        for (int k = 0; k < 128; ++k) a += sHid[k] * w2h[k * 64 + t];
        out[bi * 64 + t] = a;
    } else if (t < 67) {
        out[OUT_H + bi * 3 + (t - 64)] = sRed[16 + (t - 64)];
    }
}

extern "C" void kernel_launch(void* const* d_in, const int* in_sizes, int n_in,
                              void* d_out, int out_size, void* d_ws, size_t ws_size,
                              hipStream_t stream)
{
    const float* feats = (const float*)d_in[0];
    const float* coors = (const float*)d_in[1];
    const float* w1e   = (const float*)d_in[2];
    const float* b1e   = (const float*)d_in[3];
    const float* w2e   = (const float*)d_in[4];
    const float* b2e   = (const float*)d_in[5];
    const float* w1c   = (const float*)d_in[6];
    const float* b1c   = (const float*)d_in[7];
    const float* w2c   = (const float*)d_in[8];
    const float* b2c   = (const float*)d_in[9];
    const float* w1h   = (const float*)d_in[10];
    const float* b1h   = (const float*)d_in[11];
    const float* w2h   = (const float*)d_in[12];
    const float* b2h   = (const float*)d_in[13];
    float* out = (float*)d_out;

    float* Q1   = (float*)d_ws;                 // 1024*274 floats
    float* P2T  = Q1 + (B_ * N_) * EH;          // 2*274*512 floats
    float* w1cT = P2T + B_ * EH * N_;           // 1024 floats

    egnn_pre<<<1100, 256, 0, stream>>>(feats, w1e, b1e, w1c, Q1, P2T, w1cT);
    egnn_edge<<<1024, 256, 0, stream>>>(feats, coors, w1e, w2e, b2e, b1c,
                                        w2c, b2c, w1h, b1h, w2h, b2h,
                                        Q1, P2T, w1cT, out);
}

// Round 3
// 67.387 us; speedup vs baseline: 2.6494x; 2.6494x over previous
//
#include <hip/hip_runtime.h>
#include <math.h>
#include <stdint.h>

#define NP 288               // 274 padded to 9*32
#define OUT_H (2*512*64)

typedef _Float16 f16;
typedef __attribute__((ext_vector_type(2))) _Float16 f16x2;
typedef __attribute__((ext_vector_type(8))) _Float16 f16x8;
typedef __attribute__((ext_vector_type(4))) float f32x4;

union V8 { f16x8 v; f16x2 h[4]; };

// ---------------------------------------------------------------------------
// Kernel A: precompute (all f16, e-padded to 288 with zeros)
//   Q1[n][288]   = b1e + feats[n] @ w1e[0:64]      (i-side, includes bias)
//   P2[n][288]   = feats[n] @ w1e[64:128]          (j-side)
//   Wd[9][288]   = w1e[128+k]                      (dist-enc rows)
//   W2T[16][288] = w2e^T                           (B-frag source, e>=274 -> 0)
//   W1CB[4][16][32] = w1c[k][16T+c] (k<16, else 0) (coor-MLP A-frag source)
// ---------------------------------------------------------------------------
__global__ __launch_bounds__(256) void egnn_pre(
    const float* __restrict__ feats, const float* __restrict__ w1e,
    const float* __restrict__ b1e,   const float* __restrict__ w2e,
    const float* __restrict__ w1c,
    f16* __restrict__ Q1, f16* __restrict__ P2, f16* __restrict__ Wd,
    f16* __restrict__ W2T, f16* __restrict__ W1CB)
{
    int id = blockIdx.x * 256 + threadIdx.x;
    const int NN = 1024 * NP;
    if (id < 2 * NN) {
        int hf = id / NN, r = id % NN;
        int n = r / NP, e = r % NP;
        float a = 0.f;
        if (e < 274) {
            a = hf ? 0.f : b1e[e];
            const float* fp = feats + n * 64;
            const float* wp = w1e + hf * 64 * 274 + e;
            #pragma unroll 8
            for (int d2 = 0; d2 < 64; ++d2) a += fp[d2] * wp[d2 * 274];
        }
        (hf ? P2 : Q1)[n * NP + e] = (f16)a;
    } else {
        int x = id - 2 * NN;
        if (x < 9 * NP) {
            int e = x % NP, k = x / NP;
            Wd[x] = (f16)(e < 274 ? w1e[(128 + k) * 274 + e] : 0.f);
        } else if (x < 25 * NP) {
            int y = x - 9 * NP;
            int c2 = y / NP, e = y % NP;
            W2T[y] = (f16)(e < 274 ? w2e[e * 16 + c2] : 0.f);
        } else if (x < 25 * NP + 2048) {
            int y = x - 25 * NP;                 // 0..2047
            int T = y >> 9, rem = y & 511, c2 = rem >> 5, k = rem & 31;
            W1CB[y] = (f16)(k < 16 ? w1c[k * 64 + T * 16 + c2] : 0.f);
        }
    }
}

// ---------------------------------------------------------------------------
// Kernel B: one block per (b,i). 4 waves x 128 j each.
// Phase 1: edge MLP -> m_ij via pk-f16 VALU (pre) + MFMA (274x16 GEMV)
// Phase 2: coor MLP via MFMA (hidden^T = w1c^T @ m^T), reductions, node MLP
// ---------------------------------------------------------------------------
__global__ __launch_bounds__(256) void egnn_edge(
    const float* __restrict__ feats, const float* __restrict__ coors,
    const float* __restrict__ b2e,   const float* __restrict__ b1c,
    const float* __restrict__ w2c,   const float* __restrict__ b2cv,
    const float* __restrict__ w1h,   const float* __restrict__ b1h,
    const float* __restrict__ w2h,   const float* __restrict__ b2h,
    const f16* __restrict__ Q1,  const f16* __restrict__ P2,
    const f16* __restrict__ Wd,  const f16* __restrict__ W2T,
    const f16* __restrict__ W1CB, float* __restrict__ out)
{
    __shared__ f16   sWd[9 * NP];      // 5184 B
    __shared__ float sM[512 * 20];     // 40960 B  (cols 0..15 = m)
    __shared__ float sHid[128];
    __shared__ float sRedM[4][16];
    __shared__ float sRedC[4][3];
    __shared__ float sFin[16];

    const int bi = blockIdx.x, bb = bi >> 9;
    const int t = threadIdx.x;
    const int lane = t & 63, wv = t >> 6;
    const int c = lane & 15, g = lane >> 4;

    // stage Wd into LDS (dword copies)
    {
        const uint32_t* src = (const uint32_t*)Wd;
        uint32_t* dst = (uint32_t*)sWd;
        for (int x = t; x < 9 * NP / 2; x += 256) dst[x] = src[x];
    }
    const float b2e_c = b2e[c];
    const float cix = coors[bi * 3 + 0];
    const float ciy = coors[bi * 3 + 1];
    const float ciz = coors[bi * 3 + 2];
    __syncthreads();

    const f16* Q1r = Q1 + bi * NP;
    const f16* P2b = P2 + (bb << 9) * NP;

    // ================= Phase 1: edge MLP =================
    #pragma unroll 1
    for (int pass = 0; pass < 2; ++pass) {
        const int jbase = wv * 128 + pass * 64;

        uint32_t encPk[4][5];
        #pragma unroll
        for (int q = 0; q < 4; ++q) {
            int jg = (bb << 9) + jbase + q * 16 + c;
            float rx = cix - coors[jg * 3 + 0];
            float ry = ciy - coors[jg * 3 + 1];
            float rz = ciz - coors[jg * 3 + 2];
            float sq = rx * rx + ry * ry + rz * rz;
            float d = sq > 0.f ? sqrtf(sq) : 0.f;
            float en[9];
            #pragma unroll
            for (int k = 0; k < 4; ++k) {
                float sv, cv;
                __sincosf(d * (1.f / (float)(1 << k)), &sv, &cv);
                en[k] = sv; en[4 + k] = cv;
            }
            en[8] = d;
            #pragma unroll
            for (int p = 0; p < 4; ++p) {
                uint32_t lo = (uint32_t)__builtin_bit_cast(uint16_t, (f16)en[2 * p]);
                uint32_t hi = (uint32_t)__builtin_bit_cast(uint16_t, (f16)en[2 * p + 1]);
                encPk[q][p] = lo | (hi << 16);
            }
            encPk[q][4] = (uint32_t)__builtin_bit_cast(uint16_t, (f16)en[8]);
        }

        f32x4 acc[4] = {{0,0,0,0},{0,0,0,0},{0,0,0,0},{0,0,0,0}};

        #pragma unroll 1
        for (int s = 0; s < 9; ++s) {
            const int eo = s * 32 + g * 8;
            // Wd fragments for this K-step (registers)
            V8 wd[9];
            #pragma unroll
            for (int k = 0; k < 9; ++k)
                wd[k].v = *(const f16x8*)(sWd + k * NP + eo);
            f16x8 b8 = *(const f16x8*)(W2T + c * NP + eo);   // B-frag (w2e^T)
            f16x8 q8 = *(const f16x8*)(Q1r + eo);

            #pragma unroll
            for (int q = 0; q < 4; ++q) {
                int j = jbase + q * 16 + c;
                V8 H;
                H.v = q8 + *(const f16x8*)(P2b + j * NP + eo);
                #pragma unroll
                for (int k = 0; k < 9; ++k) {
                    uint32_t spl = __builtin_amdgcn_perm(
                        encPk[q][k >> 1], encPk[q][k >> 1],
                        (k & 1) ? 0x07060706u : 0x05040504u);
                    f16x2 e2 = __builtin_bit_cast(f16x2, spl);
                    #pragma unroll
                    for (int p = 0; p < 4; ++p)
                        H.h[p] = __builtin_elementwise_fma(wd[k].h[p], e2, H.h[p]);
                }
                const f16x2 z2 = {(_Float16)0, (_Float16)0};
                #pragma unroll
                for (int p = 0; p < 4; ++p)
                    H.h[p] = __builtin_elementwise_max(H.h[p], z2);
                acc[q] = __builtin_amdgcn_mfma_f32_16x16x32_f16(H.v, b8, acc[q], 0, 0, 0);
            }
        }
        #pragma unroll
        for (int q = 0; q < 4; ++q) {
            int jrow = jbase + q * 16 + g * 4;
            #pragma unroll
            for (int r = 0; r < 4; ++r)
                sM[(jrow + r) * 20 + c] = acc[q][r] + b2e_c;
        }
    }
    __syncthreads();

    // ================= Phase 2: coor MLP via MFMA =================
    f16x8 aW[4];
    f32x4 b1cL[4], w2cL[4];
    #pragma unroll
    for (int T = 0; T < 4; ++T) {
        aW[T] = *(const f16x8*)(W1CB + (T * 16 + c) * 32 + g * 8);
        b1cL[T] = *(const f32x4*)(b1c + T * 16 + g * 4);
        w2cL[T] = *(const f32x4*)(w2c + T * 16 + g * 4);
    }
    const float b2c0 = b2cv[0];

    float cax = 0.f, cay = 0.f, caz = 0.f;
    float macc8[8] = {0.f,0.f,0.f,0.f,0.f,0.f,0.f,0.f};

    #pragma unroll 1
    for (int jt = 0; jt < 8; ++jt) {
        const int jrow = wv * 128 + jt * 16;
        f16x8 bm = {0,0,0,0,0,0,0,0};
        if (g < 2) {
            f32x4 m0 = *(const f32x4*)(sM + (jrow + c) * 20 + g * 8);
            f32x4 m1 = *(const f32x4*)(sM + (jrow + c) * 20 + g * 8 + 4);
            #pragma unroll
            for (int p = 0; p < 4; ++p) { macc8[p] += m0[p]; macc8[4 + p] += m1[p]; }
            bm[0]=(f16)m0[0]; bm[1]=(f16)m0[1]; bm[2]=(f16)m0[2]; bm[3]=(f16)m0[3];
            bm[4]=(f16)m1[0]; bm[5]=(f16)m1[1]; bm[6]=(f16)m1[2]; bm[7]=(f16)m1[3];
        }
        f32x4 zc = {0,0,0,0};
        float cwp = 0.f;
        #pragma unroll
        for (int T = 0; T < 4; ++T) {
            f32x4 hd = __builtin_amdgcn_mfma_f32_16x16x32_f16(aW[T], bm, zc, 0, 0, 0);
            #pragma unroll
            for (int r = 0; r < 4; ++r)
                cwp += fmaxf(hd[r] + b1cL[T][r], 0.f) * w2cL[T][r];
        }
        cwp += __shfl_xor(cwp, 16);
        cwp += __shfl_xor(cwp, 32);
        float cw = cwp + b2c0;

        int jg = (bb << 9) + jrow + c;
        float rx = cix - coors[jg * 3 + 0];
        float ry = ciy - coors[jg * 3 + 1];
        float rz = ciz - coors[jg * 3 + 2];
        cax += cw * rx; cay += cw * ry; caz += cw * rz;
    }

    // m_i: reduce macc8 over the 16 c-lanes (butterfly)
    #pragma unroll
    for (int msk = 1; msk <= 8; msk <<= 1)
        #pragma unroll
        for (int p = 0; p < 8; ++p) macc8[p] += __shfl_xor(macc8[p], msk);
    if (c == 0 && g < 2) {
        #pragma unroll
        for (int p = 0; p < 8; ++p) sRedM[wv][g * 8 + p] = macc8[p];
    }
    // coors: full-wave reduce (each edge counted 4x -> scale 0.25 at the end)
    #pragma unroll
    for (int msk = 1; msk <= 32; msk <<= 1) {
        cax += __shfl_xor(cax, msk);
        cay += __shfl_xor(cay, msk);
        caz += __shfl_xor(caz, msk);
    }
    if (lane == 0) { sRedC[wv][0] = cax; sRedC[wv][1] = cay; sRedC[wv][2] = caz; }
    __syncthreads();

    if (t < 16) sFin[t] = sRedM[0][t] + sRedM[1][t] + sRedM[2][t] + sRedM[3][t];
    if (t >= 32 && t < 35) {
        int k = t - 32;
        out[OUT_H + bi * 3 + k] =
            (sRedC[0][k] + sRedC[1][k] + sRedC[2][k] + sRedC[3][k]) * 0.25f;
    }
    __syncthreads();

    // ================= node MLP =================
    if (t < 128) {
        float a = b1h[t];
        const float* fp = feats + bi * 64;
        #pragma unroll 8
        for (int k = 0; k < 64; ++k) a += fp[k] * w1h[k * 128 + t];
        #pragma unroll
        for (int k = 0; k < 16; ++k) a += sFin[k] * w1h[(64 + k) * 128 + t];
        sHid[t] = fmaxf(a, 0.f);
    }
    __syncthreads();
    if (t < 64) {
        float a = b2h[t];
        #pragma unroll 8
        for (int k = 0; k < 128; ++k) a += sHid[k] * w2h[k * 64 + t];
        out[bi * 64 + t] = a;
    }
}

extern "C" void kernel_launch(void* const* d_in, const int* in_sizes, int n_in,
                              void* d_out, int out_size, void* d_ws, size_t ws_size,
                              hipStream_t stream)
{
    const float* feats = (const float*)d_in[0];
    const float* coors = (const float*)d_in[1];
    const float* w1e   = (const float*)d_in[2];
    const float* b1e   = (const float*)d_in[3];
    const float* w2e   = (const float*)d_in[4];
    const float* b2e   = (const float*)d_in[5];
    const float* w1c   = (const float*)d_in[6];
    const float* b1c   = (const float*)d_in[7];
    const float* w2c   = (const float*)d_in[8];
    const float* b2c   = (const float*)d_in[9];
    const float* w1h   = (const float*)d_in[10];
    const float* b1h   = (const float*)d_in[11];
    const float* w2h   = (const float*)d_in[12];
    const float* b2h   = (const float*)d_in[13];
    float* out = (float*)d_out;

    char* ws = (char*)d_ws;
    f16* Q1   = (f16*)ws;                              // 589824 B
    f16* P2   = (f16*)(ws + 589824);                   // 589824 B
    f16* Wd   = (f16*)(ws + 2 * 589824);               // 5184 B
    f16* W2T  = (f16*)(ws + 2 * 589824 + 5184);        // 9216 B
    f16* W1CB = (f16*)(ws + 2 * 589824 + 5184 + 9216); // 4096 B

    egnn_pre<<<2341, 256, 0, stream>>>(feats, w1e, b1e, w2e, w1c, Q1, P2, Wd, W2T, W1CB);
    egnn_edge<<<1024, 256, 0, stream>>>(feats, coors, b2e, b1c, w2c, b2c,
                                        w1h, b1h, w2h, b2h,
                                        Q1, P2, Wd, W2T, W1CB, out);
}